// Round 3
// baseline (2261.728 us; speedup 1.0000x reference)
//
#include <hip/hip_runtime.h>
#include <math.h>

__device__ __forceinline__ float fast_rcp(float x) { return __builtin_amdgcn_rcpf(x); }

// Softplus + sigmoid with HW instructions only (v_exp_f32 / v_log_f32 / v_rcp_f32).
__device__ __forceinline__ void sp_sig(float z, float& h, float& s) {
    float az = fabsf(z);
    float e  = __expf(-az);
    float r  = fast_rcp(1.0f + e);
    h = fmaxf(z, 0.0f) + __logf(1.0f + e);
    s = (z >= 0.0f) ? r : (1.0f - r);
}

__global__ __launch_bounds__(256) void energy_kernel(
    const float* __restrict__ Fg,
    const float* __restrict__ W0, const float* __restrict__ b0,
    const float* __restrict__ W1, const float* __restrict__ b1,
    const float* __restrict__ W2, const float* __restrict__ b2,
    float* __restrict__ P, float* __restrict__ Wv, int n)
{
    // LDS weight layout:
    //   [0..255]    w0t[32][8] : {W0[0..5][k], b0[k], pad}  (32B rows -> b128)
    //   [256..1279] w1 [32][32] rows
    //   [1280..1311] b1, [1312..1343] w2, [1344] b2
    __shared__ float lw[1345];
    const int tid = threadIdx.x;
    if (tid < 32) {
        #pragma unroll
        for (int m = 0; m < 6; ++m) lw[tid * 8 + m] = W0[m * 32 + tid];
        lw[tid * 8 + 6] = b0[tid];
        lw[tid * 8 + 7] = 0.0f;
        lw[1280 + tid] = b1[tid];
        lw[1312 + tid] = W2[tid];
    }
    #pragma unroll
    for (int i = 0; i < 1024; i += 256) lw[256 + i + tid] = W1[i + tid];
    if (tid == 0) lw[1344] = b2[0];
    __syncthreads();

    int idx = blockIdx.x * blockDim.x + tid;
    if (idx >= n) return;

    const float* f = Fg + (size_t)idx * 9;

    // ---- invariants (F regs die after this block) ----
    float iv0, iv1, iv2, iv3, iv4, iv5;
    {
        float f00=f[0], f01=f[1], f02=f[2];
        float f10=f[3], f11=f[4], f12=f[5];
        float f20=f[6], f21=f[7], f22=f[8];

        float c00 = f00*f00 + f10*f10 + f20*f20;
        float c01 = f00*f01 + f10*f11 + f20*f21;
        float c02 = f00*f02 + f10*f12 + f20*f22;
        float c11 = f01*f01 + f11*f11 + f21*f21;
        float c12 = f01*f02 + f11*f12 + f21*f22;
        float c22 = f02*f02 + f12*f12 + f22*f22;

        float A00 = c11*c22 - c12*c12;
        float A01 = c02*c12 - c01*c22;
        float A02 = c01*c12 - c02*c11;
        float A11 = c00*c22 - c02*c02;
        float A12 = c01*c02 - c00*c12;
        float A22 = c00*c11 - c01*c01;

        iv0 = c00 + c11 + c22;
        iv1 = A00 + A11 + A22;
        iv2 = f00*(f11*f22 - f12*f21) - f01*(f10*f22 - f12*f20) + f02*(f10*f21 - f11*f20);
        iv3 = -iv2;
        iv4 = c00*c00 + c11*c11 + c22*c22;
        iv5 = A00*A00 + A11*A11 + A22*A22;
    }

    // ---- fused layer0 + layer1: h0[k] produced and consumed immediately ----
    float s0[32];
    float z1[32];
    #pragma unroll
    for (int j = 0; j < 32; ++j) z1[j] = lw[1280 + j];

    #pragma unroll
    for (int k = 0; k < 32; ++k) {
        float4 wa = *(const float4*)(lw + k * 8);      // W0[0..3][k]
        float4 wb = *(const float4*)(lw + k * 8 + 4);  // W0[4],W0[5],b0,pad
        float z = wb.z;
        z = fmaf(iv0, wa.x, z);
        z = fmaf(iv1, wa.y, z);
        z = fmaf(iv2, wa.z, z);
        z = fmaf(iv3, wa.w, z);
        z = fmaf(iv4, wb.x, z);
        z = fmaf(iv5, wb.y, z);
        float hk, sk;
        sp_sig(z, hk, sk);
        s0[k] = sk;
        #pragma unroll
        for (int j4 = 0; j4 < 8; ++j4) {
            float4 w = *(const float4*)(lw + 256 + k * 32 + j4 * 4);
            z1[j4*4+0] = fmaf(hk, w.x, z1[j4*4+0]);
            z1[j4*4+1] = fmaf(hk, w.y, z1[j4*4+1]);
            z1[j4*4+2] = fmaf(hk, w.z, z1[j4*4+2]);
            z1[j4*4+3] = fmaf(hk, w.w, z1[j4*4+3]);
        }
    }

    // ---- output layer + g1 (z1 -> g1 in place) ----
    float g1[32];
    {
        float o0=0.f, o1=0.f, o2=0.f, o3=0.f;
        #pragma unroll
        for (int j = 0; j < 32; ++j) {
            float h1, s1;
            sp_sig(z1[j], h1, s1);
            float w2 = lw[1312 + j];
            if ((j & 3) == 0)      o0 = fmaf(h1, w2, o0);
            else if ((j & 3) == 1) o1 = fmaf(h1, w2, o1);
            else if ((j & 3) == 2) o2 = fmaf(h1, w2, o2);
            else                   o3 = fmaf(h1, w2, o3);
            g1[j] = w2 * s1;
        }
        Wv[idx] = (o0 + o1) + (o2 + o3) + lw[1344];
    }

    // ---- backward: d[m] = dOut/d iv[m] ----
    float d0=0.f, d1=0.f, d2r=0.f, d3r=0.f, d4=0.f, d5=0.f;
    #pragma unroll
    for (int k = 0; k < 32; ++k) {
        float p0=0.f, p1=0.f, p2=0.f, p3=0.f;
        #pragma unroll
        for (int j4 = 0; j4 < 8; ++j4) {
            float4 w = *(const float4*)(lw + 256 + k * 32 + j4 * 4);
            p0 = fmaf(w.x, g1[j4*4+0], p0);
            p1 = fmaf(w.y, g1[j4*4+1], p1);
            p2 = fmaf(w.z, g1[j4*4+2], p2);
            p3 = fmaf(w.w, g1[j4*4+3], p3);
        }
        float g0k = ((p0 + p1) + (p2 + p3)) * s0[k];
        float4 wa = *(const float4*)(lw + k * 8);
        float4 wb = *(const float4*)(lw + k * 8 + 4);
        d0  = fmaf(wa.x, g0k, d0);
        d1  = fmaf(wa.y, g0k, d1);
        d2r = fmaf(wa.z, g0k, d2r);
        d3r = fmaf(wa.w, g0k, d3r);
        d4  = fmaf(wb.x, g0k, d4);
        d5  = fmaf(wb.y, g0k, d5);
    }

    // ---- epilogue: reload F (L3-warm), P = F*M + (d2-d3)*cof(F) ----
    float f00=f[0], f01=f[1], f02=f[2];
    float f10=f[3], f11=f[4], f12=f[5];
    float f20=f[6], f21=f[7], f22=f[8];

    float c00 = f00*f00 + f10*f10 + f20*f20;
    float c01 = f00*f01 + f10*f11 + f20*f21;
    float c02 = f00*f02 + f10*f12 + f20*f22;
    float c11 = f01*f01 + f11*f11 + f21*f21;
    float c12 = f01*f02 + f11*f12 + f21*f22;
    float c22 = f02*f02 + f12*f12 + f22*f22;

    float A00 = c11*c22 - c12*c12;
    float A01 = c02*c12 - c01*c22;
    float A02 = c01*c12 - c02*c11;
    float A11 = c00*c22 - c02*c02;
    float A12 = c01*c02 - c00*c12;
    float A22 = c00*c11 - c01*c01;

    float cf00 = f11*f22 - f12*f21;
    float cf01 = f12*f20 - f10*f22;
    float cf02 = f10*f21 - f11*f20;
    float cf10 = f02*f21 - f01*f22;
    float cf11 = f00*f22 - f02*f20;
    float cf12 = f01*f20 - f00*f21;
    float cf20 = f01*f12 - f02*f11;
    float cf21 = f02*f10 - f00*f12;
    float cf22 = f00*f11 - f01*f10;
    float J  = f00*cf00 + f01*cf01 + f02*cf02;
    float I1 = c00 + c11 + c22;
    float I11v = A00*A00 + A11*A11 + A22*A22;

    float inv2 = 2.0f * fast_rcp(J * J);

    float T00 = A00*A00*A00 + A11*A01*A01 + A22*A02*A02;
    float T01 = A00*A00*A01 + A11*A01*A11 + A22*A02*A12;
    float T02 = A00*A00*A02 + A11*A01*A12 + A22*A02*A22;
    float T11 = A00*A01*A01 + A11*A11*A11 + A22*A12*A12;
    float T12 = A00*A01*A02 + A11*A11*A12 + A22*A12*A22;
    float T22 = A00*A02*A02 + A11*A12*A12 + A22*A22*A22;

    float G00 = inv2 * (I11v*A00 - T00);
    float G01 = inv2 * (I11v*A01 - T01);
    float G02 = inv2 * (I11v*A02 - T02);
    float G11e= inv2 * (I11v*A11 - T11);
    float G12 = inv2 * (I11v*A12 - T12);
    float G22 = inv2 * (I11v*A22 - T22);

    float aJ  = d2r - d3r;
    float t1  = 2.0f * d0;
    float t2  = 2.0f * d1;
    float t7  = 4.0f * d4;
    float t11 = 2.0f * d5;

    float m00 = t1 + t2*(I1 - c00) + t7*c00 + t11*G00;
    float m01 =      -t2*c01               + t11*G01;
    float m02 =      -t2*c02               + t11*G02;
    float m11 = t1 + t2*(I1 - c11) + t7*c11 + t11*G11e;
    float m12 =      -t2*c12               + t11*G12;
    float m22 = t1 + t2*(I1 - c22) + t7*c22 + t11*G22;

    float* p = P + (size_t)idx * 9;
    p[0] = f00*m00 + f01*m01 + f02*m02 + aJ*cf00;
    p[1] = f00*m01 + f01*m11 + f02*m12 + aJ*cf01;
    p[2] = f00*m02 + f01*m12 + f02*m22 + aJ*cf02;
    p[3] = f10*m00 + f11*m01 + f12*m02 + aJ*cf10;
    p[4] = f10*m01 + f11*m11 + f12*m12 + aJ*cf11;
    p[5] = f10*m02 + f11*m12 + f12*m22 + aJ*cf12;
    p[6] = f20*m00 + f21*m01 + f22*m02 + aJ*cf20;
    p[7] = f20*m01 + f21*m11 + f22*m12 + aJ*cf21;
    p[8] = f20*m02 + f21*m12 + f22*m22 + aJ*cf22;
}

extern "C" void kernel_launch(void* const* d_in, const int* in_sizes, int n_in,
                              void* d_out, int out_size, void* d_ws, size_t ws_size,
                              hipStream_t stream) {
    const float* F  = (const float*)d_in[0];
    const float* W0 = (const float*)d_in[1];
    const float* b0 = (const float*)d_in[2];
    const float* W1 = (const float*)d_in[3];
    const float* b1 = (const float*)d_in[4];
    const float* W2 = (const float*)d_in[5];
    const float* b2 = (const float*)d_in[6];
    int n = in_sizes[0] / 9;
    float* out = (float*)d_out;
    float* P  = out;                       // [n,3,3] flat
    float* Wv = out + (size_t)n * 9;       // [n,1] flat

    int block = 256;
    int grid = (n + block - 1) / block;
    hipLaunchKernelGGL(energy_kernel, dim3(grid), dim3(block), 0, stream,
                       F, W0, b0, W1, b1, W2, b2, P, Wv, n);
}